// Round 6
// baseline (1129.868 us; speedup 1.0000x reference)
//
#include <hip/hip_runtime.h>

#define B_SZ  32768
#define S_MC  4
#define D_IN  256
#define LAT   8
#define NBINS 300
#define KDIM  1323
#define RNK   4

typedef float f32x4 __attribute__((ext_vector_type(4)));

constexpr int TPB   = 64;                       // ONE wave per block/row
constexpr int NPASS = S_MC + 1;                 // 4 samples + mean path
constexpr int KPT   = (KDIM + TPB - 1) / TPB;   // 21 slots; only slot 20 is ragged

// Structure rationale (R4 post-mortem): kernel is latency/convoy-bound, not BW-
// bound. One wave per row => all softmax reductions are in-wave shfl (no LDS
// roundtrip, no cross-wave barrier rendezvous); 32768 independent blocks give
// the scheduler ~20-30 uncoupled waves/CU to hide L1/L2 latency.

__global__ __launch_bounds__(TPB, 4) void cp_profile_kernel(
    const float* __restrict__ x,       // (B, 256)
    const float* __restrict__ eps,     // (S, B, 8)
    const float* __restrict__ A,       // (300, 4)
    const float* __restrict__ Bm,      // (1323, 4)
    const float* __restrict__ C,       // (8, 4)
    const float* __restrict__ bias,    // (300, 1323)
    const float* __restrict__ mu_w,    // (8, 256)
    const float* __restrict__ mu_b,    // (8,)
    const float* __restrict__ std_w,   // (8, 256)
    const float* __restrict__ std_b,   // (8,)
    const int*   __restrict__ glab,    // (B,)
    float* __restrict__ out)
{
    __shared__ float muh_s[LAT];
    __shared__ float stdh_s[LAT];
    __shared__ float w_s[NPASS][RNK];

    const int t = threadIdx.x;
    const int b = blockIdx.x;
    const int g = glab[b];

    // ---- 16 dot products, 4 lanes each (d = t>>2 in [0,16), chunk c = t&3) ----
    {
        const int d = t >> 2, c = t & 3;
        const f32x4* x4 = reinterpret_cast<const f32x4*>(x + (size_t)b * D_IN);
        const f32x4* W4 = reinterpret_cast<const f32x4*>(
            (d < LAT) ? (mu_w + d * D_IN) : (std_w + (d - LAT) * D_IN));
        float a = 0.f;
        #pragma unroll
        for (int i = 0; i < 16; ++i) {
            const f32x4 xv = x4[c * 16 + i];
            const f32x4 wv = W4[c * 16 + i];
            a += xv.x * wv.x + xv.y * wv.y + xv.z * wv.z + xv.w * wv.w;
        }
        a += __shfl_xor(a, 1, 64);     // reduce over chunk bits (c)
        a += __shfl_xor(a, 2, 64);
        if (c == 0) {
            if (d < LAT) {
                muh_s[d] = a + mu_b[d];
            } else {
                const float y = a + std_b[d - LAT];
                stdh_s[d - LAT] = fmaxf(y, 0.f) + log1pf(expf(-fabsf(y)));
            }
        }
    }
    __syncthreads();                   // single-wave barrier: near-free

    // ---- CP weights w[s][r] = A_n[r] * z[s][r]; s==4 is the mean path ----
    if (t < 20) {
        const int s = t >> 2, r = t & 3;
        const float* ep = eps + ((size_t)(s < S_MC ? s : 0) * B_SZ + b) * LAT;
        float z = 0.f;
        #pragma unroll
        for (int j = 0; j < LAT; ++j) {
            float h = muh_s[j];
            if (s < S_MC) h += stdh_s[j] * ep[j];
            z += h * C[j * RNK + r];
        }
        w_s[s][r] = A[g * RNK + r] * z;
    }
    // small outputs (mu_h / std_h, fp32)
    const size_t base_small = (size_t)NPASS * B_SZ * KDIM;
    if (t >= 32 && t < 40)
        out[base_small + (size_t)b * LAT + (t - 32)] = muh_s[t - 32];
    if (t >= 40 && t < 48)
        out[base_small + (size_t)B_SZ * LAT + (size_t)b * LAT + (t - 40)] = stdh_s[t - 40];
    __syncthreads();                   // single-wave barrier: near-free

    float wr[NPASS][RNK];
    #pragma unroll
    for (int s = 0; s < NPASS; ++s)
        #pragma unroll
        for (int r = 0; r < RNK; ++r)
            wr[s][r] = w_s[s][r];

    // ---- bias row -> registers (21 slots; only j==20 ragged: k<1323 iff t<43) ----
    const float* biasg = bias + (size_t)g * KDIM;
    float bn[KPT];
    #pragma unroll
    for (int j = 0; j < KPT; ++j) {
        const int k = t + TPB * j;
        bn[j] = (k < KDIM) ? biasg[k] : 0.f;
    }

    const f32x4* B4 = reinterpret_cast<const f32x4*>(Bm);

    auto LG = [&](const f32x4& r4, float bi, int s) -> float {
        return fmaf(wr[s][0], r4.x,
               fmaf(wr[s][1], r4.y,
               fmaf(wr[s][2], r4.z, wr[s][3] * r4.w))) + bi;
    };

    // ---- sweep 1: logits -> running max (B re-read from L1 each sweep) ----
    float lmax[NPASS];
    #pragma unroll
    for (int s = 0; s < NPASS; ++s) lmax[s] = -INFINITY;
    #pragma unroll
    for (int j = 0; j < KPT; ++j) {
        const int k = t + TPB * j;
        if (k < KDIM) {
            const f32x4 bv = B4[k];
            #pragma unroll
            for (int s = 0; s < NPASS; ++s)
                lmax[s] = fmaxf(lmax[s], LG(bv, bn[j], s));
        }
    }
    #pragma unroll
    for (int s = 0; s < NPASS; ++s)
        #pragma unroll
        for (int off = 32; off > 0; off >>= 1)
            lmax[s] = fmaxf(lmax[s], __shfl_xor(lmax[s], off, 64));
    // all lanes now hold the row max in lmax[s]; no LDS, no barrier

    // ---- sweep 2: recompute -> exp -> running sum ----
    float lsum[NPASS];
    #pragma unroll
    for (int s = 0; s < NPASS; ++s) lsum[s] = 0.f;
    #pragma unroll
    for (int j = 0; j < KPT; ++j) {
        const int k = t + TPB * j;
        if (k < KDIM) {
            const f32x4 bv = B4[k];
            #pragma unroll
            for (int s = 0; s < NPASS; ++s)
                lsum[s] += __expf(LG(bv, bn[j], s) - lmax[s]);
        }
    }
    #pragma unroll
    for (int s = 0; s < NPASS; ++s)
        #pragma unroll
        for (int off = 32; off > 0; off >>= 1)
            lsum[s] += __shfl_xor(lsum[s], off, 64);

    float inv[NPASS];
    #pragma unroll
    for (int s = 0; s < NPASS; ++s) inv[s] = 1.f / lsum[s];

    // ---- sweep 3: recompute -> exp -> normalize -> streamed stores ----
    #pragma unroll
    for (int j = 0; j < KPT; ++j) {
        const int k = t + TPB * j;
        if (k < KDIM) {
            const f32x4 bv = B4[k];
            #pragma unroll
            for (int s = 0; s < NPASS; ++s) {
                const size_t ob = (s < S_MC)
                    ? ((size_t)((size_t)s * B_SZ + b) * KDIM)
                    : ((size_t)S_MC * B_SZ * KDIM + (size_t)b * KDIM);
                __builtin_nontemporal_store(
                    __expf(LG(bv, bn[j], s) - lmax[s]) * inv[s], out + ob + k);
            }
        }
    }
}

extern "C" void kernel_launch(void* const* d_in, const int* in_sizes, int n_in,
                              void* d_out, int out_size, void* d_ws, size_t ws_size,
                              hipStream_t stream) {
    const float* x     = (const float*)d_in[0];
    const float* eps   = (const float*)d_in[1];
    const float* A     = (const float*)d_in[2];
    const float* Bm    = (const float*)d_in[3];
    const float* C     = (const float*)d_in[4];
    const float* bias  = (const float*)d_in[5];
    const float* mu_w  = (const float*)d_in[6];
    const float* mu_b  = (const float*)d_in[7];
    const float* std_w = (const float*)d_in[8];
    const float* std_b = (const float*)d_in[9];
    const int*   glab  = (const int*)d_in[10];
    float* out = (float*)d_out;

    cp_profile_kernel<<<B_SZ, TPB, 0, stream>>>(
        x, eps, A, Bm, C, bias, mu_w, mu_b, std_w, std_b, glab, out);
}